// Round 5
// baseline (1166.598 us; speedup 1.0000x reference)
//
#include <hip/hip_runtime.h>

#define N_NODES 100000
#define N_EDGES 1600000
#define F_IN    501
#define H1      8
#define C1      8
#define D1      64   // H1*C1
#define NCLS    40
#define NBKT    782  // ceil(N_NODES/128), 128 nodes per bucket

typedef __attribute__((ext_vector_type(8))) short bf16x8;
typedef __attribute__((ext_vector_type(4))) float f32x4;

__device__ __forceinline__ float lrelu(float x) { return x > 0.f ? x : 0.2f * x; }

__device__ __forceinline__ unsigned short f2bf(float f) {
    unsigned u = __float_as_uint(f);
    u += 0x7FFFu + ((u >> 16) & 1u);
    return (unsigned short)(u >> 16);
}
__device__ __forceinline__ float bf2f(unsigned short u) {
    return __uint_as_float(((unsigned)u) << 16);
}

// ---------------------------------------------------------------------------
// GEMM1 (MFMA bf16): xh1b[N,64] = bf16( x[N,501] @ W1[501,64] )
// 64x64 tile, BK=64, 4 waves (16 rows each) -> grid 1563 for occupancy.
// ---------------------------------------------------------------------------
__global__ __launch_bounds__(256) void gemm1(const float* __restrict__ x,
                                             const float* __restrict__ W1,
                                             unsigned short* __restrict__ xh1b) {
    __shared__ __align__(16) unsigned short As[64][72]; // [row][k]
    __shared__ __align__(16) unsigned short Bs[64][72]; // [col][k]

    const int tid  = threadIdx.x;
    const int lane = tid & 63;
    const int wave = tid >> 6;
    const int row0 = blockIdx.x * 64;
    const int lr   = lane & 15;
    const int lk   = (lane >> 4) * 8;

    f32x4 acc[4] = {};

    for (int k0 = 0; k0 < F_IN; k0 += 64) {
        // stage A: 64 rows x 64 k; thread -> row tid>>2, 16-k segment
        {
            int r    = tid >> 2;
            int seg  = (tid & 3) * 16;
            int grow = row0 + r;
            int gk   = k0 + seg;
            const float* p = x + (size_t)grow * F_IN + gk;
            #pragma unroll
            for (int j = 0; j < 16; j += 2) {
                float v0 = 0.f, v1 = 0.f;
                if (grow < N_NODES) {
                    if (gk + j     < F_IN) v0 = p[j];
                    if (gk + j + 1 < F_IN) v1 = p[j + 1];
                }
                *(ushort2*)&As[r][seg + j] = make_ushort2(f2bf(v0), f2bf(v1));
            }
        }
        // stage B: W1 64k x 64n transposed -> Bs[n][k]
        {
            int n  = tid & 63;
            int ch = (tid >> 6) * 16;
            #pragma unroll
            for (int j = 0; j < 16; j += 2) {
                int k = k0 + ch + j;
                unsigned short w0 = (k     < F_IN) ? f2bf(W1[(size_t)k * D1 + n])       : 0;
                unsigned short w1 = (k + 1 < F_IN) ? f2bf(W1[(size_t)(k + 1) * D1 + n]) : 0;
                *(ushort2*)&Bs[n][ch + j] = make_ushort2(w0, w1);
            }
        }
        __syncthreads();

        bf16x8 a[2], bb[4][2];
        #pragma unroll
        for (int s2 = 0; s2 < 2; ++s2)
            a[s2] = *(const bf16x8*)&As[wave * 16 + lr][s2 * 32 + lk];
        #pragma unroll
        for (int n = 0; n < 4; ++n)
            #pragma unroll
            for (int s2 = 0; s2 < 2; ++s2)
                bb[n][s2] = *(const bf16x8*)&Bs[n * 16 + lr][s2 * 32 + lk];

        #pragma unroll
        for (int n = 0; n < 4; ++n)
            #pragma unroll
            for (int s2 = 0; s2 < 2; ++s2)
                acc[n] = __builtin_amdgcn_mfma_f32_16x16x32_bf16(a[s2], bb[n][s2], acc[n], 0, 0, 0);
        __syncthreads();
    }

    // epilogue: row = row0 + 16*wave + (lane>>4)*4 + r, col = 16n + (lane&15)
    int rbase = row0 + wave * 16 + (lane >> 4) * 4;
    #pragma unroll
    for (int n = 0; n < 4; ++n) {
        int col = n * 16 + (lane & 15);
        #pragma unroll
        for (int r = 0; r < 4; ++r) {
            int grow = rbase + r;
            if (grow < N_NODES) xh1b[(size_t)grow * D1 + col] = f2bf(acc[n][r]);
        }
    }
}

// ---------------------------------------------------------------------------
// A1: per-(node,head) attention coefficients for layer 1 (bf16 features)
// ---------------------------------------------------------------------------
__global__ void a1k(const unsigned short* __restrict__ xh1b,
                    const float* __restrict__ att_s, const float* __restrict__ att_d,
                    const int* __restrict__ idxp,
                    float* __restrict__ a_src, float* __restrict__ a_dst) {
    int gid = blockIdx.x * blockDim.x + threadIdx.x;
    if (gid >= N_NODES * H1) return;
    int n = gid >> 3, h = gid & 7;
    float sign = (idxp[0] == 1) ? -1.f : 1.f;
    uint4 u = *(const uint4*)(xh1b + (size_t)n * D1 + h * C1);
    float v[8];
    v[0] = bf2f((unsigned short)(u.x & 0xffff)); v[1] = bf2f((unsigned short)(u.x >> 16));
    v[2] = bf2f((unsigned short)(u.y & 0xffff)); v[3] = bf2f((unsigned short)(u.y >> 16));
    v[4] = bf2f((unsigned short)(u.z & 0xffff)); v[5] = bf2f((unsigned short)(u.z >> 16));
    v[6] = bf2f((unsigned short)(u.w & 0xffff)); v[7] = bf2f((unsigned short)(u.w >> 16));
    float ss = 0.f, sd = 0.f;
    #pragma unroll
    for (int c = 0; c < C1; ++c) {
        ss += v[c] * att_s[h * C1 + c];
        sd += v[c] * att_d[h * C1 + c];
    }
    a_src[gid] = sign * ss;
    a_dst[gid] = sign * sd;
}

// ---------------------------------------------------------------------------
// Bucketed CSR build (782 buckets x 128 nodes)
// ---------------------------------------------------------------------------
__global__ void k_bhist(const int* __restrict__ ei, int* __restrict__ bcnt) {
    int e = blockIdx.x * blockDim.x + threadIdx.x;
    if (e >= N_EDGES) return;
    atomicAdd(&bcnt[ei[N_EDGES + e] >> 7], 1);
}

__global__ __launch_bounds__(1024) void k_bscan(const int* __restrict__ bcnt,
                                                int* __restrict__ bbase,
                                                int* __restrict__ bofs,
                                                int* __restrict__ rowptr) {
    __shared__ int s[1024];
    int t = threadIdx.x;
    int v = (t < NBKT) ? bcnt[t] : 0;
    s[t] = v;
    __syncthreads();
    for (int off = 1; off < 1024; off <<= 1) {
        int x = 0;
        if (t >= off) x = s[t - off];
        __syncthreads();
        if (t >= off) s[t] += x;
        __syncthreads();
    }
    if (t < NBKT) { int e = s[t] - v; bbase[t] = e; bofs[t] = e; }
    if (t == 0)   { bbase[NBKT] = N_EDGES; rowptr[N_NODES] = N_EDGES; }
}

// scatter packed (src<<7 | dst&127) into bucket-contiguous regions
__global__ void k_bscatter(const int* __restrict__ ei, int* __restrict__ bofs,
                           int* __restrict__ tmp) {
    int e = blockIdx.x * blockDim.x + threadIdx.x;
    if (e >= N_EDGES) return;
    int s = ei[e], d = ei[N_EDGES + e];
    int p = atomicAdd(&bofs[d >> 7], 1);
    tmp[p] = (s << 7) | (d & 127);
}

// per-bucket: local hist + scan -> rowptr, then node-sorted ssrc
__global__ __launch_bounds__(256) void k_bucket(const int* __restrict__ tmp,
                                                const int* __restrict__ bbase,
                                                int* __restrict__ rowptr,
                                                int* __restrict__ ssrc) {
    __shared__ int hist[128], sc[128], ofs[128];
    int b = blockIdx.x, t = threadIdx.x;
    int lo = bbase[b], hi = bbase[b + 1];
    if (t < 128) hist[t] = 0;
    __syncthreads();
    for (int i = lo + t; i < hi; i += 256)
        atomicAdd(&hist[tmp[i] & 127], 1);
    __syncthreads();
    if (t < 128) sc[t] = hist[t];
    __syncthreads();
    for (int off = 1; off < 128; off <<= 1) {
        int x = 0;
        if (t < 128 && t >= off) x = sc[t - off];
        __syncthreads();
        if (t < 128 && t >= off) sc[t] += x;
        __syncthreads();
    }
    if (t < 128) {
        int base = lo + sc[t] - hist[t];   // exclusive prefix
        int n = (b << 7) + t;
        if (n < N_NODES) rowptr[n] = base;
        ofs[t] = base;
    }
    __syncthreads();
    for (int i = lo + t; i < hi; i += 256) {
        int v = tmp[i];
        int p = atomicAdd(&ofs[v & 127], 1);
        ssrc[p] = v >> 7;
    }
}

// ---------------------------------------------------------------------------
// AGG1: one wave per destination; 4 edges in flight (quarter-waves).
// Lane li (0..15) covers channels 4li..4li+3 (head = li>>1).
// ---------------------------------------------------------------------------
__global__ __launch_bounds__(256) void agg1(const int* __restrict__ rowptr,
                                            const int* __restrict__ ssrc,
                                            const unsigned short* __restrict__ xh1b,
                                            const float* __restrict__ a_src,
                                            const float* __restrict__ a_dst,
                                            unsigned short* __restrict__ hb) {
    int wid  = (blockIdx.x * 256 + threadIdx.x) >> 6;
    int lane = threadIdx.x & 63;
    if (wid >= N_NODES) return;
    const int d  = wid;
    const int li = lane & 15;
    const int q  = lane >> 4;
    const int hh = li >> 1;

    const float adh = a_dst[d * H1 + hh];
    float a0 = 0.f, a1 = 0.f, a2 = 0.f, a3 = 0.f, den = 0.f;
    if (q == 0) {
        float e0 = __expf(lrelu(a_src[d * H1 + hh] + adh));
        ushort4 v = *(const ushort4*)&xh1b[(size_t)d * D1 + (li << 2)];
        a0 = e0 * bf2f(v.x); a1 = e0 * bf2f(v.y);
        a2 = e0 * bf2f(v.z); a3 = e0 * bf2f(v.w);
        den = e0;
    }

    const int beg = rowptr[d], end = rowptr[d + 1];
    for (int p = beg + q; p < end; p += 4) {
        int s = ssrc[p];
        float e = __expf(lrelu(a_src[s * H1 + hh] + adh));
        ushort4 v = *(const ushort4*)&xh1b[(size_t)s * D1 + (li << 2)];
        a0 = fmaf(e, bf2f(v.x), a0);
        a1 = fmaf(e, bf2f(v.y), a1);
        a2 = fmaf(e, bf2f(v.z), a2);
        a3 = fmaf(e, bf2f(v.w), a3);
        den += e;
    }

    a0 += __shfl_xor(a0, 16); a0 += __shfl_xor(a0, 32);
    a1 += __shfl_xor(a1, 16); a1 += __shfl_xor(a1, 32);
    a2 += __shfl_xor(a2, 16); a2 += __shfl_xor(a2, 32);
    a3 += __shfl_xor(a3, 16); a3 += __shfl_xor(a3, 32);
    den += __shfl_xor(den, 16); den += __shfl_xor(den, 32);

    if (lane < 16) {
        float inv = 1.f / (den + 1e-16f);
        float v0 = a0 * inv, v1 = a1 * inv, v2 = a2 * inv, v3 = a3 * inv;
        v0 = v0 > 0.f ? v0 : (__expf(v0) - 1.f);
        v1 = v1 > 0.f ? v1 : (__expf(v1) - 1.f);
        v2 = v2 > 0.f ? v2 : (__expf(v2) - 1.f);
        v3 = v3 > 0.f ? v3 : (__expf(v3) - 1.f);
        ushort4 r;
        r.x = f2bf(v0); r.y = f2bf(v1); r.z = f2bf(v2); r.w = f2bf(v3);
        *(ushort4*)&hb[(size_t)d * D1 + (li << 2)] = r;
    }
}

// ---------------------------------------------------------------------------
// GEMM2: xh2b[N,40] = bf16( h[N,64] @ W2[64,40] )
// ---------------------------------------------------------------------------
__global__ void gemm2(const unsigned short* __restrict__ hb,
                      const float* __restrict__ W2,
                      unsigned short* __restrict__ xh2b) {
    int gid = blockIdx.x * blockDim.x + threadIdx.x;
    if (gid >= N_NODES * NCLS) return;
    int n = gid / NCLS, c = gid % NCLS;
    const uint4* hr = (const uint4*)(hb + (size_t)n * D1);
    float s = 0.f;
    #pragma unroll
    for (int q = 0; q < 8; ++q) {
        uint4 u = hr[q];
        int k = q * 8;
        s = fmaf(bf2f((unsigned short)(u.x & 0xffff)), W2[(k + 0) * NCLS + c], s);
        s = fmaf(bf2f((unsigned short)(u.x >> 16)),    W2[(k + 1) * NCLS + c], s);
        s = fmaf(bf2f((unsigned short)(u.y & 0xffff)), W2[(k + 2) * NCLS + c], s);
        s = fmaf(bf2f((unsigned short)(u.y >> 16)),    W2[(k + 3) * NCLS + c], s);
        s = fmaf(bf2f((unsigned short)(u.z & 0xffff)), W2[(k + 4) * NCLS + c], s);
        s = fmaf(bf2f((unsigned short)(u.z >> 16)),    W2[(k + 5) * NCLS + c], s);
        s = fmaf(bf2f((unsigned short)(u.w & 0xffff)), W2[(k + 6) * NCLS + c], s);
        s = fmaf(bf2f((unsigned short)(u.w >> 16)),    W2[(k + 7) * NCLS + c], s);
    }
    xh2b[gid] = f2bf(s);
}

// ---------------------------------------------------------------------------
// A2: per-node attention coefficients for layer 2 (bf16 features)
// ---------------------------------------------------------------------------
__global__ void a2k(const unsigned short* __restrict__ xh2b,
                    const float* __restrict__ att_s2, const float* __restrict__ att_d2,
                    const int* __restrict__ idxp,
                    float* __restrict__ a_src2, float* __restrict__ a_dst2) {
    int n = blockIdx.x * blockDim.x + threadIdx.x;
    if (n >= N_NODES) return;
    float sign = (idxp[0] == 1) ? -1.f : 1.f;
    const uint4* xr = (const uint4*)(xh2b + (size_t)n * NCLS);
    float ss = 0.f, sd = 0.f;
    #pragma unroll
    for (int q = 0; q < 5; ++q) {
        uint4 u = xr[q];
        int k = q * 8;
        float v[8];
        v[0] = bf2f((unsigned short)(u.x & 0xffff)); v[1] = bf2f((unsigned short)(u.x >> 16));
        v[2] = bf2f((unsigned short)(u.y & 0xffff)); v[3] = bf2f((unsigned short)(u.y >> 16));
        v[4] = bf2f((unsigned short)(u.z & 0xffff)); v[5] = bf2f((unsigned short)(u.z >> 16));
        v[6] = bf2f((unsigned short)(u.w & 0xffff)); v[7] = bf2f((unsigned short)(u.w >> 16));
        #pragma unroll
        for (int j = 0; j < 8; ++j) {
            ss += v[j] * att_s2[k + j];
            sd += v[j] * att_d2[k + j];
        }
    }
    a_src2[n] = sign * ss;
    a_dst2[n] = sign * sd;
}

// ---------------------------------------------------------------------------
// AGG2: one wave per destination; 4 edges in flight; lanes li<10 carry
// channels 4li..4li+3. Fused self-loop, normalize, bias -> out (fp32).
// ---------------------------------------------------------------------------
__global__ __launch_bounds__(256) void agg2(const int* __restrict__ rowptr,
                                            const int* __restrict__ ssrc,
                                            const unsigned short* __restrict__ xh2b,
                                            const float* __restrict__ a_src2,
                                            const float* __restrict__ a_dst2,
                                            const float* __restrict__ bias2,
                                            float* __restrict__ out) {
    int wid  = (blockIdx.x * 256 + threadIdx.x) >> 6;
    int lane = threadIdx.x & 63;
    if (wid >= N_NODES) return;
    const int d  = wid;
    const int li = lane & 15;
    const int q  = lane >> 4;
    const bool act = li < (NCLS / 4);

    const float adh = a_dst2[d];
    float a0 = 0.f, a1 = 0.f, a2 = 0.f, a3 = 0.f, den = 0.f;
    if (q == 0) {
        float e0 = __expf(lrelu(a_src2[d] + adh));
        if (act) {
            ushort4 v = *(const ushort4*)&xh2b[(size_t)d * NCLS + (li << 2)];
            a0 = e0 * bf2f(v.x); a1 = e0 * bf2f(v.y);
            a2 = e0 * bf2f(v.z); a3 = e0 * bf2f(v.w);
        }
        den = e0;
    }

    const int beg = rowptr[d], end = rowptr[d + 1];
    for (int p = beg + q; p < end; p += 4) {
        int s = ssrc[p];
        float e = __expf(lrelu(a_src2[s] + adh));
        if (act) {
            ushort4 v = *(const ushort4*)&xh2b[(size_t)s * NCLS + (li << 2)];
            a0 = fmaf(e, bf2f(v.x), a0);
            a1 = fmaf(e, bf2f(v.y), a1);
            a2 = fmaf(e, bf2f(v.z), a2);
            a3 = fmaf(e, bf2f(v.w), a3);
        }
        den += e;
    }

    a0 += __shfl_xor(a0, 16); a0 += __shfl_xor(a0, 32);
    a1 += __shfl_xor(a1, 16); a1 += __shfl_xor(a1, 32);
    a2 += __shfl_xor(a2, 16); a2 += __shfl_xor(a2, 32);
    a3 += __shfl_xor(a3, 16); a3 += __shfl_xor(a3, 32);
    den += __shfl_xor(den, 16); den += __shfl_xor(den, 32);

    if (lane < 16 && act) {
        float inv = 1.f / (den + 1e-16f);
        float4 bv = *(const float4*)&bias2[li << 2];
        float4 r;
        r.x = a0 * inv + bv.x;
        r.y = a1 * inv + bv.y;
        r.z = a2 * inv + bv.z;
        r.w = a3 * inv + bv.w;
        *(float4*)&out[(size_t)d * NCLS + (li << 2)] = r;
    }
}

// ---------------------------------------------------------------------------
extern "C" void kernel_launch(void* const* d_in, const int* in_sizes, int n_in,
                              void* d_out, int out_size, void* d_ws, size_t ws_size,
                              hipStream_t stream) {
    const float* x    = (const float*)d_in[0];
    const float* W1   = (const float*)d_in[1];
    const float* as1w = (const float*)d_in[2];
    const float* ad1w = (const float*)d_in[3];
    const float* W2   = (const float*)d_in[4];
    const float* as2w = (const float*)d_in[5];
    const float* ad2w = (const float*)d_in[6];
    const float* b2   = (const float*)d_in[7];
    const int*   ei   = (const int*)d_in[8];
    const int*   idxp = (const int*)d_in[9];
    float* out = (float*)d_out;

    // workspace layout
    unsigned short* xh1b = (unsigned short*)d_ws;        // [N*64] bf16
    unsigned short* hb   = xh1b + (size_t)N_NODES * D1;  // [N*64] bf16
    unsigned short* xh2b = hb + (size_t)N_NODES * D1;    // [N*40] bf16
    float* as1 = (float*)(xh2b + (size_t)N_NODES * NCLS);
    float* ad1 = as1 + (size_t)N_NODES * H1;
    float* as2 = ad1 + (size_t)N_NODES * H1;             // [N]
    float* ad2 = as2 + N_NODES;
    int* bcnt   = (int*)(ad2 + N_NODES);                 // [NBKT]
    int* bbase  = bcnt + NBKT;                           // [NBKT+1]
    int* bofs   = bbase + (NBKT + 1);                    // [NBKT]
    int* rowptr = bofs + NBKT;                           // [N+1]
    int* tmp    = rowptr + (N_NODES + 1);                // [E]
    int* ssrc   = tmp + N_EDGES;                         // [E]

    // ---- bucketed CSR build ----
    hipMemsetAsync(bcnt, 0, (size_t)NBKT * sizeof(int), stream);
    k_bhist<<<(N_EDGES + 255) / 256, 256, 0, stream>>>(ei, bcnt);
    k_bscan<<<1, 1024, 0, stream>>>(bcnt, bbase, bofs, rowptr);
    k_bscatter<<<(N_EDGES + 255) / 256, 256, 0, stream>>>(ei, bofs, tmp);
    k_bucket<<<NBKT, 256, 0, stream>>>(tmp, bbase, rowptr, ssrc);

    // ---- layer 1 ----
    gemm1<<<(N_NODES + 63) / 64, 256, 0, stream>>>(x, W1, xh1b);
    a1k<<<(N_NODES * H1 + 255) / 256, 256, 0, stream>>>(xh1b, as1w, ad1w, idxp, as1, ad1);
    agg1<<<(N_NODES * 64 + 255) / 256, 256, 0, stream>>>(rowptr, ssrc, xh1b, as1, ad1, hb);

    // ---- layer 2 ----
    gemm2<<<(N_NODES * NCLS + 255) / 256, 256, 0, stream>>>(hb, W2, xh2b);
    a2k<<<(N_NODES + 255) / 256, 256, 0, stream>>>(xh2b, as2w, ad2w, idxp, as2, ad2);
    agg2<<<(N_NODES * 64 + 255) / 256, 256, 0, stream>>>(rowptr, ssrc, xh2b, as2, ad2, b2, out);
}

// Round 6
// 477.358 us; speedup vs baseline: 2.4439x; 2.4439x over previous
//
#include <hip/hip_runtime.h>

#define N_NODES 100000
#define N_EDGES 1600000
#define F_IN    501
#define H1      8
#define C1      8
#define D1      64   // H1*C1
#define NCLS    40

typedef __attribute__((ext_vector_type(8))) short bf16x8;
typedef __attribute__((ext_vector_type(4))) float f32x4;

__device__ __forceinline__ float lrelu(float x) { return x > 0.f ? x : 0.2f * x; }

__device__ __forceinline__ unsigned short f2bf(float f) {
    unsigned u = __float_as_uint(f);
    u += 0x7FFFu + ((u >> 16) & 1u);
    return (unsigned short)(u >> 16);
}
__device__ __forceinline__ float bf2f(unsigned short u) {
    return __uint_as_float(((unsigned)u) << 16);
}

// ---------------------------------------------------------------------------
// GEMM1 (MFMA bf16): xh1b[N,64] = bf16( x[N,501] @ W1[501,64] )
// 64x64 tile, BK=32, 4 waves (16 rows each) -> grid 1563 for occupancy.
// ---------------------------------------------------------------------------
__global__ __launch_bounds__(256) void gemm1(const float* __restrict__ x,
                                             const float* __restrict__ W1,
                                             unsigned short* __restrict__ xh1b) {
    __shared__ __align__(16) unsigned short As[64][40]; // [row][k], 80B stride
    __shared__ __align__(16) unsigned short Bs[64][40]; // [col][k] (W1 transposed)

    const int tid  = threadIdx.x;
    const int lane = tid & 63;
    const int wave = tid >> 6;
    const int row0 = blockIdx.x * 64;
    const int lr   = lane & 15;
    const int lk   = (lane >> 4) * 8;

    f32x4 acc[4] = {};

    for (int k0 = 0; k0 < F_IN; k0 += 32) {
        // stage A tile: 64 rows x 32 k (8 threads x 4k per row, 2 row-groups)
        #pragma unroll
        for (int i = 0; i < 2; ++i) {
            int r    = (tid >> 3) + i * 32;     // 0..63
            int kl   = (tid & 7) * 4;           // 0..28
            int grow = row0 + r;
            int gk   = k0 + kl;
            float v0 = 0.f, v1 = 0.f, v2 = 0.f, v3 = 0.f;
            if (grow < N_NODES) {
                const float* p = x + (size_t)grow * F_IN + gk;
                if (gk + 3 < F_IN) { v0 = p[0]; v1 = p[1]; v2 = p[2]; v3 = p[3]; }
                else {
                    if (gk + 0 < F_IN) v0 = p[0];
                    if (gk + 1 < F_IN) v1 = p[1];
                    if (gk + 2 < F_IN) v2 = p[2];
                }
            }
            ushort2* dst = (ushort2*)&As[r][kl];
            dst[0] = make_ushort2(f2bf(v0), f2bf(v1));
            dst[1] = make_ushort2(f2bf(v2), f2bf(v3));
        }
        // stage W tile transposed: Bs[n][k], 32k x 64n
        #pragma unroll
        for (int i = 0; i < 2; ++i) {
            int e  = tid + i * 256;             // 0..511
            int n  = e & 63;
            int kl = (e >> 6) * 4;              // 0..28
            int gk = k0 + kl;
            unsigned short w0 = (gk + 0 < F_IN) ? f2bf(W1[(size_t)(gk + 0) * D1 + n]) : 0;
            unsigned short w1 = (gk + 1 < F_IN) ? f2bf(W1[(size_t)(gk + 1) * D1 + n]) : 0;
            unsigned short w2 = (gk + 2 < F_IN) ? f2bf(W1[(size_t)(gk + 2) * D1 + n]) : 0;
            unsigned short w3 = (gk + 3 < F_IN) ? f2bf(W1[(size_t)(gk + 3) * D1 + n]) : 0;
            ushort2* dst = (ushort2*)&Bs[n][kl];
            dst[0] = make_ushort2(w0, w1);
            dst[1] = make_ushort2(w2, w3);
        }
        __syncthreads();

        bf16x8 a = *(const bf16x8*)&As[wave * 16 + lr][lk];
        bf16x8 b[4];
        #pragma unroll
        for (int n = 0; n < 4; ++n)
            b[n] = *(const bf16x8*)&Bs[n * 16 + lr][lk];

        #pragma unroll
        for (int n = 0; n < 4; ++n)
            acc[n] = __builtin_amdgcn_mfma_f32_16x16x32_bf16(a, b[n], acc[n], 0, 0, 0);
        __syncthreads();
    }

    // epilogue: row = row0 + 16*wave + (lane>>4)*4 + r, col = 16n + (lane&15)
    int rbase = row0 + wave * 16 + (lane >> 4) * 4;
    #pragma unroll
    for (int n = 0; n < 4; ++n) {
        int col = n * 16 + (lane & 15);
        #pragma unroll
        for (int r = 0; r < 4; ++r) {
            int grow = rbase + r;
            if (grow < N_NODES) xh1b[(size_t)grow * D1 + col] = f2bf(acc[n][r]);
        }
    }
}

// ---------------------------------------------------------------------------
// A1: per-(node,head) attention coefficients for layer 1 (bf16 features)
// ---------------------------------------------------------------------------
__global__ void a1k(const unsigned short* __restrict__ xh1b,
                    const float* __restrict__ att_s, const float* __restrict__ att_d,
                    const int* __restrict__ idxp,
                    float* __restrict__ a_src, float* __restrict__ a_dst) {
    int gid = blockIdx.x * blockDim.x + threadIdx.x;
    if (gid >= N_NODES * H1) return;
    int n = gid >> 3, h = gid & 7;
    float sign = (idxp[0] == 1) ? -1.f : 1.f;
    uint4 u = *(const uint4*)(xh1b + (size_t)n * D1 + h * C1);
    float v[8];
    v[0] = bf2f((unsigned short)(u.x & 0xffff)); v[1] = bf2f((unsigned short)(u.x >> 16));
    v[2] = bf2f((unsigned short)(u.y & 0xffff)); v[3] = bf2f((unsigned short)(u.y >> 16));
    v[4] = bf2f((unsigned short)(u.z & 0xffff)); v[5] = bf2f((unsigned short)(u.z >> 16));
    v[6] = bf2f((unsigned short)(u.w & 0xffff)); v[7] = bf2f((unsigned short)(u.w >> 16));
    float ss = 0.f, sd = 0.f;
    #pragma unroll
    for (int c = 0; c < C1; ++c) {
        ss += v[c] * att_s[h * C1 + c];
        sd += v[c] * att_d[h * C1 + c];
    }
    a_src[gid] = sign * ss;
    a_dst[gid] = sign * sd;
}

// ---------------------------------------------------------------------------
// CSR build: histogram -> scan -> scatter  (R4 proven scheme)
// ---------------------------------------------------------------------------
__global__ void k_hist(const int* __restrict__ ei, int* __restrict__ cnt) {
    int e = blockIdx.x * blockDim.x + threadIdx.x;
    if (e >= N_EDGES) return;
    atomicAdd(&cnt[ei[N_EDGES + e]], 1);
}

__global__ __launch_bounds__(256) void k_scan1(const int* __restrict__ cnt,
                                               int* __restrict__ pre,
                                               int* __restrict__ bsum) {
    __shared__ int s[256];
    int t = threadIdx.x;
    int base = blockIdx.x * 1024 + t * 4;
    int v[4], sum = 0;
    #pragma unroll
    for (int i = 0; i < 4; ++i) {
        v[i] = (base + i < N_NODES) ? cnt[base + i] : 0;
        sum += v[i];
    }
    s[t] = sum;
    __syncthreads();
    for (int off = 1; off < 256; off <<= 1) {
        int x = 0;
        if (t >= off) x = s[t - off];
        __syncthreads();
        if (t >= off) s[t] += x;
        __syncthreads();
    }
    int run = s[t] - sum;
    if (t == 255) bsum[blockIdx.x] = s[255];
    #pragma unroll
    for (int i = 0; i < 4; ++i) {
        if (base + i < N_NODES) pre[base + i] = run;
        run += v[i];
    }
}

__global__ void k_scan2(int* __restrict__ bsum, int nb) {
    __shared__ int s[128];
    int t = threadIdx.x;
    int v = (t < nb) ? bsum[t] : 0;
    s[t] = v;
    __syncthreads();
    for (int off = 1; off < 128; off <<= 1) {
        int x = 0;
        if (t >= off) x = s[t - off];
        __syncthreads();
        if (t >= off) s[t] += x;
        __syncthreads();
    }
    if (t < nb) bsum[t] = s[t] - v;
}

__global__ void k_scan3(const int* __restrict__ pre, const int* __restrict__ bsum,
                        int* __restrict__ rowptr, int* __restrict__ wofs) {
    int i = blockIdx.x * blockDim.x + threadIdx.x;
    if (i < N_NODES) {
        int r = pre[i] + bsum[i >> 10];
        rowptr[i] = r;
        wofs[i]   = r;
    } else if (i == N_NODES) {
        rowptr[N_NODES] = N_EDGES;
    }
}

__global__ void k_scatter(const int* __restrict__ ei, int* __restrict__ wofs,
                          int* __restrict__ ssrc) {
    int e = blockIdx.x * blockDim.x + threadIdx.x;
    if (e >= N_EDGES) return;
    int s = ei[e], d = ei[N_EDGES + e];
    int p = atomicAdd(&wofs[d], 1);
    ssrc[p] = s;
}

// ---------------------------------------------------------------------------
// AGG1: one wave per destination; 4 edges in flight (quarter-waves).
// Lane li (0..15) covers channels 4li..4li+3 (head = li>>1).
// ---------------------------------------------------------------------------
__global__ __launch_bounds__(256) void agg1(const int* __restrict__ rowptr,
                                            const int* __restrict__ ssrc,
                                            const unsigned short* __restrict__ xh1b,
                                            const float* __restrict__ a_src,
                                            const float* __restrict__ a_dst,
                                            unsigned short* __restrict__ hb) {
    int wid  = (blockIdx.x * 256 + threadIdx.x) >> 6;
    int lane = threadIdx.x & 63;
    if (wid >= N_NODES) return;
    const int d  = wid;
    const int li = lane & 15;
    const int q  = lane >> 4;
    const int hh = li >> 1;

    const float adh = a_dst[d * H1 + hh];
    float a0 = 0.f, a1 = 0.f, a2 = 0.f, a3 = 0.f, den = 0.f;
    if (q == 0) {
        float e0 = __expf(lrelu(a_src[d * H1 + hh] + adh));
        ushort4 v = *(const ushort4*)&xh1b[(size_t)d * D1 + (li << 2)];
        a0 = e0 * bf2f(v.x); a1 = e0 * bf2f(v.y);
        a2 = e0 * bf2f(v.z); a3 = e0 * bf2f(v.w);
        den = e0;
    }

    const int beg = rowptr[d], end = rowptr[d + 1];
    for (int p = beg + q; p < end; p += 4) {
        int s = ssrc[p];
        float e = __expf(lrelu(a_src[s * H1 + hh] + adh));
        ushort4 v = *(const ushort4*)&xh1b[(size_t)s * D1 + (li << 2)];
        a0 = fmaf(e, bf2f(v.x), a0);
        a1 = fmaf(e, bf2f(v.y), a1);
        a2 = fmaf(e, bf2f(v.z), a2);
        a3 = fmaf(e, bf2f(v.w), a3);
        den += e;
    }

    a0 += __shfl_xor(a0, 16); a0 += __shfl_xor(a0, 32);
    a1 += __shfl_xor(a1, 16); a1 += __shfl_xor(a1, 32);
    a2 += __shfl_xor(a2, 16); a2 += __shfl_xor(a2, 32);
    a3 += __shfl_xor(a3, 16); a3 += __shfl_xor(a3, 32);
    den += __shfl_xor(den, 16); den += __shfl_xor(den, 32);

    if (lane < 16) {
        float inv = 1.f / (den + 1e-16f);
        float v0 = a0 * inv, v1 = a1 * inv, v2 = a2 * inv, v3 = a3 * inv;
        v0 = v0 > 0.f ? v0 : (__expf(v0) - 1.f);
        v1 = v1 > 0.f ? v1 : (__expf(v1) - 1.f);
        v2 = v2 > 0.f ? v2 : (__expf(v2) - 1.f);
        v3 = v3 > 0.f ? v3 : (__expf(v3) - 1.f);
        ushort4 r;
        r.x = f2bf(v0); r.y = f2bf(v1); r.z = f2bf(v2); r.w = f2bf(v3);
        *(ushort4*)&hb[(size_t)d * D1 + (li << 2)] = r;
    }
}

// ---------------------------------------------------------------------------
// GEMM2: xh2b[N,40] = bf16( h[N,64] @ W2[64,40] )
// ---------------------------------------------------------------------------
__global__ void gemm2(const unsigned short* __restrict__ hb,
                      const float* __restrict__ W2,
                      unsigned short* __restrict__ xh2b) {
    int gid = blockIdx.x * blockDim.x + threadIdx.x;
    if (gid >= N_NODES * NCLS) return;
    int n = gid / NCLS, c = gid % NCLS;
    const uint4* hr = (const uint4*)(hb + (size_t)n * D1);
    float s = 0.f;
    #pragma unroll
    for (int q = 0; q < 8; ++q) {
        uint4 u = hr[q];
        int k = q * 8;
        s = fmaf(bf2f((unsigned short)(u.x & 0xffff)), W2[(k + 0) * NCLS + c], s);
        s = fmaf(bf2f((unsigned short)(u.x >> 16)),    W2[(k + 1) * NCLS + c], s);
        s = fmaf(bf2f((unsigned short)(u.y & 0xffff)), W2[(k + 2) * NCLS + c], s);
        s = fmaf(bf2f((unsigned short)(u.y >> 16)),    W2[(k + 3) * NCLS + c], s);
        s = fmaf(bf2f((unsigned short)(u.z & 0xffff)), W2[(k + 4) * NCLS + c], s);
        s = fmaf(bf2f((unsigned short)(u.z >> 16)),    W2[(k + 5) * NCLS + c], s);
        s = fmaf(bf2f((unsigned short)(u.w & 0xffff)), W2[(k + 6) * NCLS + c], s);
        s = fmaf(bf2f((unsigned short)(u.w >> 16)),    W2[(k + 7) * NCLS + c], s);
    }
    xh2b[gid] = f2bf(s);
}

// ---------------------------------------------------------------------------
// A2: per-node attention coefficients for layer 2 (bf16 features)
// ---------------------------------------------------------------------------
__global__ void a2k(const unsigned short* __restrict__ xh2b,
                    const float* __restrict__ att_s2, const float* __restrict__ att_d2,
                    const int* __restrict__ idxp,
                    float* __restrict__ a_src2, float* __restrict__ a_dst2) {
    int n = blockIdx.x * blockDim.x + threadIdx.x;
    if (n >= N_NODES) return;
    float sign = (idxp[0] == 1) ? -1.f : 1.f;
    const uint4* xr = (const uint4*)(xh2b + (size_t)n * NCLS);
    float ss = 0.f, sd = 0.f;
    #pragma unroll
    for (int q = 0; q < 5; ++q) {
        uint4 u = xr[q];
        int k = q * 8;
        float v[8];
        v[0] = bf2f((unsigned short)(u.x & 0xffff)); v[1] = bf2f((unsigned short)(u.x >> 16));
        v[2] = bf2f((unsigned short)(u.y & 0xffff)); v[3] = bf2f((unsigned short)(u.y >> 16));
        v[4] = bf2f((unsigned short)(u.z & 0xffff)); v[5] = bf2f((unsigned short)(u.z >> 16));
        v[6] = bf2f((unsigned short)(u.w & 0xffff)); v[7] = bf2f((unsigned short)(u.w >> 16));
        #pragma unroll
        for (int j = 0; j < 8; ++j) {
            ss += v[j] * att_s2[k + j];
            sd += v[j] * att_d2[k + j];
        }
    }
    a_src2[n] = sign * ss;
    a_dst2[n] = sign * sd;
}

// ---------------------------------------------------------------------------
// AGG2: one wave per destination; 4 edges in flight; lanes li<10 carry
// channels 4li..4li+3. Fused self-loop, normalize, bias -> out (fp32).
// ---------------------------------------------------------------------------
__global__ __launch_bounds__(256) void agg2(const int* __restrict__ rowptr,
                                            const int* __restrict__ ssrc,
                                            const unsigned short* __restrict__ xh2b,
                                            const float* __restrict__ a_src2,
                                            const float* __restrict__ a_dst2,
                                            const float* __restrict__ bias2,
                                            float* __restrict__ out) {
    int wid  = (blockIdx.x * 256 + threadIdx.x) >> 6;
    int lane = threadIdx.x & 63;
    if (wid >= N_NODES) return;
    const int d  = wid;
    const int li = lane & 15;
    const int q  = lane >> 4;
    const bool act = li < (NCLS / 4);

    const float adh = a_dst2[d];
    float a0 = 0.f, a1 = 0.f, a2 = 0.f, a3 = 0.f, den = 0.f;
    if (q == 0) {
        float e0 = __expf(lrelu(a_src2[d] + adh));
        if (act) {
            ushort4 v = *(const ushort4*)&xh2b[(size_t)d * NCLS + (li << 2)];
            a0 = e0 * bf2f(v.x); a1 = e0 * bf2f(v.y);
            a2 = e0 * bf2f(v.z); a3 = e0 * bf2f(v.w);
        }
        den = e0;
    }

    const int beg = rowptr[d], end = rowptr[d + 1];
    for (int p = beg + q; p < end; p += 4) {
        int s = ssrc[p];
        float e = __expf(lrelu(a_src2[s] + adh));
        if (act) {
            ushort4 v = *(const ushort4*)&xh2b[(size_t)s * NCLS + (li << 2)];
            a0 = fmaf(e, bf2f(v.x), a0);
            a1 = fmaf(e, bf2f(v.y), a1);
            a2 = fmaf(e, bf2f(v.z), a2);
            a3 = fmaf(e, bf2f(v.w), a3);
        }
        den += e;
    }

    a0 += __shfl_xor(a0, 16); a0 += __shfl_xor(a0, 32);
    a1 += __shfl_xor(a1, 16); a1 += __shfl_xor(a1, 32);
    a2 += __shfl_xor(a2, 16); a2 += __shfl_xor(a2, 32);
    a3 += __shfl_xor(a3, 16); a3 += __shfl_xor(a3, 32);
    den += __shfl_xor(den, 16); den += __shfl_xor(den, 32);

    if (lane < 16 && act) {
        float inv = 1.f / (den + 1e-16f);
        float4 bv = *(const float4*)&bias2[li << 2];
        float4 r;
        r.x = a0 * inv + bv.x;
        r.y = a1 * inv + bv.y;
        r.z = a2 * inv + bv.z;
        r.w = a3 * inv + bv.w;
        *(float4*)&out[(size_t)d * NCLS + (li << 2)] = r;
    }
}

// ---------------------------------------------------------------------------
extern "C" void kernel_launch(void* const* d_in, const int* in_sizes, int n_in,
                              void* d_out, int out_size, void* d_ws, size_t ws_size,
                              hipStream_t stream) {
    const float* x    = (const float*)d_in[0];
    const float* W1   = (const float*)d_in[1];
    const float* as1w = (const float*)d_in[2];
    const float* ad1w = (const float*)d_in[3];
    const float* W2   = (const float*)d_in[4];
    const float* as2w = (const float*)d_in[5];
    const float* ad2w = (const float*)d_in[6];
    const float* b2   = (const float*)d_in[7];
    const int*   ei   = (const int*)d_in[8];
    const int*   idxp = (const int*)d_in[9];
    float* out = (float*)d_out;

    // workspace layout
    unsigned short* xh1b = (unsigned short*)d_ws;        // [N*64] bf16
    unsigned short* hb   = xh1b + (size_t)N_NODES * D1;  // [N*64] bf16
    unsigned short* xh2b = hb + (size_t)N_NODES * D1;    // [N*40] bf16
    float* as1 = (float*)(xh2b + (size_t)N_NODES * NCLS);
    float* ad1 = as1 + (size_t)N_NODES * H1;
    float* as2 = ad1 + (size_t)N_NODES * H1;             // [N]
    float* ad2 = as2 + N_NODES;
    int*   cnt    = (int*)(ad2 + N_NODES);               // [N]
    int*   pre    = cnt + N_NODES;                       // [N]
    int*   rowptr = pre + N_NODES;                       // [N+1]
    int*   wofs   = rowptr + (N_NODES + 1);              // [N]
    int*   bsum   = wofs + N_NODES;                      // [128]
    int*   ssrc   = bsum + 128;                          // [E]

    const int NB = (N_NODES + 1023) / 1024;

    // ---- CSR build ----
    hipMemsetAsync(cnt, 0, (size_t)N_NODES * sizeof(int), stream);
    k_hist<<<(N_EDGES + 255) / 256, 256, 0, stream>>>(ei, cnt);
    k_scan1<<<NB, 256, 0, stream>>>(cnt, pre, bsum);
    k_scan2<<<1, 128, 0, stream>>>(bsum, NB);
    k_scan3<<<(N_NODES + 256) / 256, 256, 0, stream>>>(pre, bsum, rowptr, wofs);
    k_scatter<<<(N_EDGES + 255) / 256, 256, 0, stream>>>(ei, wofs, ssrc);

    // ---- layer 1 ----
    gemm1<<<(N_NODES + 63) / 64, 256, 0, stream>>>(x, W1, xh1b);
    a1k<<<(N_NODES * H1 + 255) / 256, 256, 0, stream>>>(xh1b, as1w, ad1w, idxp, as1, ad1);
    agg1<<<(N_NODES * 64 + 255) / 256, 256, 0, stream>>>(rowptr, ssrc, xh1b, as1, ad1, hb);

    // ---- layer 2 ----
    gemm2<<<(N_NODES * NCLS + 255) / 256, 256, 0, stream>>>(hb, W2, xh2b);
    a2k<<<(N_NODES + 255) / 256, 256, 0, stream>>>(xh2b, as2w, ad2w, idxp, as2, ad2);
    agg2<<<(N_NODES * 64 + 255) / 256, 256, 0, stream>>>(rowptr, ssrc, xh2b, as2, ad2, b2, out);
}

// Round 7
// 459.767 us; speedup vs baseline: 2.5374x; 1.0383x over previous
//
#include <hip/hip_runtime.h>

#define N_NODES 100000
#define N_EDGES 1600000
#define F_IN    501
#define H1      8
#define C1      8
#define D1      64   // H1*C1
#define NCLS    40

#define G_GEMM  1563          // ceil(N_NODES/64)
#define G_SCAT  512           // scatter blocks in fused kernel
#define NKSTEP  16            // ceil(F_IN/32)

typedef __attribute__((ext_vector_type(8))) short bf16x8;
typedef __attribute__((ext_vector_type(4))) float f32x4;

__device__ __forceinline__ float lrelu(float x) { return x > 0.f ? x : 0.2f * x; }

__device__ __forceinline__ unsigned short f2bf(float f) {
    unsigned u = __float_as_uint(f);
    u += 0x7FFFu + ((u >> 16) & 1u);
    return (unsigned short)(u >> 16);
}
__device__ __forceinline__ float bf2f(unsigned short u) {
    return __uint_as_float(((unsigned)u) << 16);
}

// ---------------------------------------------------------------------------
// FUSED: gemm1 (MFMA bf16, reg-staged double-buffered) || k_scatter.
// Blocks [0,G_GEMM): 64x64-tile GEMM, BK=32.
// Blocks [G_GEMM, G_GEMM+G_SCAT): grid-stride CSR scatter.
// The two halves bottleneck on different resources (mem pipeline vs atomic
// latency) and overlap on the CUs.
// ---------------------------------------------------------------------------
__global__ __launch_bounds__(256) void gemm1_scatter(
        const float* __restrict__ x, const float* __restrict__ W1,
        unsigned short* __restrict__ xh1b,
        const int* __restrict__ ei, int* __restrict__ wofs,
        int* __restrict__ ssrc) {

    __shared__ __align__(16) unsigned short As[2][64][40]; // [buf][row][k], 80B stride
    __shared__ __align__(16) unsigned short Bs[2][64][40]; // [buf][col][k]

    if (blockIdx.x >= G_GEMM) {
        // ---------------- scatter part ----------------
        int t0 = (blockIdx.x - G_GEMM) * 256 + threadIdx.x;
        for (int e = t0; e < N_EDGES; e += G_SCAT * 256) {
            int s = ei[e], d = ei[N_EDGES + e];
            int p = atomicAdd(&wofs[d], 1);
            ssrc[p] = s;
        }
        return;
    }

    // ---------------- GEMM part ----------------
    const int tid  = threadIdx.x;
    const int lane = tid & 63;
    const int wave = tid >> 6;
    const int row0 = blockIdx.x * 64;
    const int lr   = lane & 15;
    const int lk   = (lane >> 4) * 8;

    // staging assignment: A: 4 threads/row x 8 k; B: 4 threads/col x 8 k
    const int ar = tid >> 2;            // 0..63
    const int ak = (tid & 3) * 8;       // 0,8,16,24
    const int bn = tid & 63;            // 0..63
    const int bk = (tid >> 6) * 8;      // 0,8,16,24
    const int agrow = row0 + ar;
    const float* aptr = x + (size_t)agrow * F_IN;
    const bool arow_ok = (agrow < N_NODES);

    float av[8], bv[8];
    f32x4 acc[4] = {};

    // load tile k0 into regs
    #define LOAD_TILE(k0)                                                     \
        {                                                                     \
            _Pragma("unroll")                                                 \
            for (int j = 0; j < 8; ++j) {                                     \
                int gka = (k0) + ak + j;                                      \
                av[j] = (arow_ok && gka < F_IN) ? aptr[gka] : 0.f;            \
                int gkb = (k0) + bk + j;                                      \
                bv[j] = (gkb < F_IN) ? W1[(size_t)gkb * D1 + bn] : 0.f;       \
            }                                                                 \
        }

    // convert + write regs into LDS buffer b
    #define WRITE_TILE(b)                                                     \
        {                                                                     \
            uint4 ua, ub;                                                     \
            ua.x = (unsigned)f2bf(av[0]) | ((unsigned)f2bf(av[1]) << 16);     \
            ua.y = (unsigned)f2bf(av[2]) | ((unsigned)f2bf(av[3]) << 16);     \
            ua.z = (unsigned)f2bf(av[4]) | ((unsigned)f2bf(av[5]) << 16);     \
            ua.w = (unsigned)f2bf(av[6]) | ((unsigned)f2bf(av[7]) << 16);     \
            ub.x = (unsigned)f2bf(bv[0]) | ((unsigned)f2bf(bv[1]) << 16);     \
            ub.y = (unsigned)f2bf(bv[2]) | ((unsigned)f2bf(bv[3]) << 16);     \
            ub.z = (unsigned)f2bf(bv[4]) | ((unsigned)f2bf(bv[5]) << 16);     \
            ub.w = (unsigned)f2bf(bv[6]) | ((unsigned)f2bf(bv[7]) << 16);     \
            *(uint4*)&As[b][ar][ak] = ua;                                     \
            *(uint4*)&Bs[b][bn][bk] = ub;                                     \
        }

    LOAD_TILE(0);
    WRITE_TILE(0);
    __syncthreads();

    for (int step = 0; step < NKSTEP; ++step) {
        const int cur = step & 1;
        bf16x8 a  = *(const bf16x8*)&As[cur][wave * 16 + lr][lk];
        bf16x8 b0 = *(const bf16x8*)&Bs[cur][ 0 + lr][lk];
        bf16x8 b1 = *(const bf16x8*)&Bs[cur][16 + lr][lk];
        bf16x8 b2 = *(const bf16x8*)&Bs[cur][32 + lr][lk];
        bf16x8 b3 = *(const bf16x8*)&Bs[cur][48 + lr][lk];

        if (step + 1 < NKSTEP) LOAD_TILE((step + 1) * 32);   // loads in flight

        acc[0] = __builtin_amdgcn_mfma_f32_16x16x32_bf16(a, b0, acc[0], 0, 0, 0);
        acc[1] = __builtin_amdgcn_mfma_f32_16x16x32_bf16(a, b1, acc[1], 0, 0, 0);
        acc[2] = __builtin_amdgcn_mfma_f32_16x16x32_bf16(a, b2, acc[2], 0, 0, 0);
        acc[3] = __builtin_amdgcn_mfma_f32_16x16x32_bf16(a, b3, acc[3], 0, 0, 0);

        if (step + 1 < NKSTEP) WRITE_TILE(cur ^ 1);          // waits vmcnt here
        __syncthreads();
    }

    // epilogue: row = row0 + 16*wave + (lane>>4)*4 + r, col = 16n + (lane&15)
    int rbase = row0 + wave * 16 + (lane >> 4) * 4;
    #pragma unroll
    for (int n = 0; n < 4; ++n) {
        int col = n * 16 + (lane & 15);
        #pragma unroll
        for (int r = 0; r < 4; ++r) {
            int grow = rbase + r;
            if (grow < N_NODES) xh1b[(size_t)grow * D1 + col] = f2bf(acc[n][r]);
        }
    }
    #undef LOAD_TILE
    #undef WRITE_TILE
}

// ---------------------------------------------------------------------------
// A1: per-(node,head) attention coefficients for layer 1 (bf16 features)
// ---------------------------------------------------------------------------
__global__ void a1k(const unsigned short* __restrict__ xh1b,
                    const float* __restrict__ att_s, const float* __restrict__ att_d,
                    const int* __restrict__ idxp,
                    float* __restrict__ a_src, float* __restrict__ a_dst) {
    int gid = blockIdx.x * blockDim.x + threadIdx.x;
    if (gid >= N_NODES * H1) return;
    int n = gid >> 3, h = gid & 7;
    float sign = (idxp[0] == 1) ? -1.f : 1.f;
    uint4 u = *(const uint4*)(xh1b + (size_t)n * D1 + h * C1);
    float v[8];
    v[0] = bf2f((unsigned short)(u.x & 0xffff)); v[1] = bf2f((unsigned short)(u.x >> 16));
    v[2] = bf2f((unsigned short)(u.y & 0xffff)); v[3] = bf2f((unsigned short)(u.y >> 16));
    v[4] = bf2f((unsigned short)(u.z & 0xffff)); v[5] = bf2f((unsigned short)(u.z >> 16));
    v[6] = bf2f((unsigned short)(u.w & 0xffff)); v[7] = bf2f((unsigned short)(u.w >> 16));
    float ss = 0.f, sd = 0.f;
    #pragma unroll
    for (int c = 0; c < C1; ++c) {
        ss += v[c] * att_s[h * C1 + c];
        sd += v[c] * att_d[h * C1 + c];
    }
    a_src[gid] = sign * ss;
    a_dst[gid] = sign * sd;
}

// ---------------------------------------------------------------------------
// CSR build: histogram -> scan (scatter lives in the fused kernel)
// ---------------------------------------------------------------------------
__global__ void k_hist(const int* __restrict__ ei, int* __restrict__ cnt) {
    int e = blockIdx.x * blockDim.x + threadIdx.x;
    if (e >= N_EDGES) return;
    atomicAdd(&cnt[ei[N_EDGES + e]], 1);
}

__global__ __launch_bounds__(256) void k_scan1(const int* __restrict__ cnt,
                                               int* __restrict__ pre,
                                               int* __restrict__ bsum) {
    __shared__ int s[256];
    int t = threadIdx.x;
    int base = blockIdx.x * 1024 + t * 4;
    int v[4], sum = 0;
    #pragma unroll
    for (int i = 0; i < 4; ++i) {
        v[i] = (base + i < N_NODES) ? cnt[base + i] : 0;
        sum += v[i];
    }
    s[t] = sum;
    __syncthreads();
    for (int off = 1; off < 256; off <<= 1) {
        int x = 0;
        if (t >= off) x = s[t - off];
        __syncthreads();
        if (t >= off) s[t] += x;
        __syncthreads();
    }
    int run = s[t] - sum;
    if (t == 255) bsum[blockIdx.x] = s[255];
    #pragma unroll
    for (int i = 0; i < 4; ++i) {
        if (base + i < N_NODES) pre[base + i] = run;
        run += v[i];
    }
}

__global__ void k_scan2(int* __restrict__ bsum, int nb) {
    __shared__ int s[128];
    int t = threadIdx.x;
    int v = (t < nb) ? bsum[t] : 0;
    s[t] = v;
    __syncthreads();
    for (int off = 1; off < 128; off <<= 1) {
        int x = 0;
        if (t >= off) x = s[t - off];
        __syncthreads();
        if (t >= off) s[t] += x;
        __syncthreads();
    }
    if (t < nb) bsum[t] = s[t] - v;
}

__global__ void k_scan3(const int* __restrict__ pre, const int* __restrict__ bsum,
                        int* __restrict__ rowptr, int* __restrict__ wofs) {
    int i = blockIdx.x * blockDim.x + threadIdx.x;
    if (i < N_NODES) {
        int r = pre[i] + bsum[i >> 10];
        rowptr[i] = r;
        wofs[i]   = r;
    } else if (i == N_NODES) {
        rowptr[N_NODES] = N_EDGES;
    }
}

// ---------------------------------------------------------------------------
// AGG1: one wave per destination; 4 edges in flight (quarter-waves).
// ---------------------------------------------------------------------------
__global__ __launch_bounds__(256) void agg1(const int* __restrict__ rowptr,
                                            const int* __restrict__ ssrc,
                                            const unsigned short* __restrict__ xh1b,
                                            const float* __restrict__ a_src,
                                            const float* __restrict__ a_dst,
                                            unsigned short* __restrict__ hb) {
    int wid  = (blockIdx.x * 256 + threadIdx.x) >> 6;
    int lane = threadIdx.x & 63;
    if (wid >= N_NODES) return;
    const int d  = wid;
    const int li = lane & 15;
    const int q  = lane >> 4;
    const int hh = li >> 1;

    const float adh = a_dst[d * H1 + hh];
    float a0 = 0.f, a1 = 0.f, a2 = 0.f, a3 = 0.f, den = 0.f;
    if (q == 0) {
        float e0 = __expf(lrelu(a_src[d * H1 + hh] + adh));
        ushort4 v = *(const ushort4*)&xh1b[(size_t)d * D1 + (li << 2)];
        a0 = e0 * bf2f(v.x); a1 = e0 * bf2f(v.y);
        a2 = e0 * bf2f(v.z); a3 = e0 * bf2f(v.w);
        den = e0;
    }

    const int beg = rowptr[d], end = rowptr[d + 1];
    for (int p = beg + q; p < end; p += 4) {
        int s = ssrc[p];
        float e = __expf(lrelu(a_src[s * H1 + hh] + adh));
        ushort4 v = *(const ushort4*)&xh1b[(size_t)s * D1 + (li << 2)];
        a0 = fmaf(e, bf2f(v.x), a0);
        a1 = fmaf(e, bf2f(v.y), a1);
        a2 = fmaf(e, bf2f(v.z), a2);
        a3 = fmaf(e, bf2f(v.w), a3);
        den += e;
    }

    a0 += __shfl_xor(a0, 16); a0 += __shfl_xor(a0, 32);
    a1 += __shfl_xor(a1, 16); a1 += __shfl_xor(a1, 32);
    a2 += __shfl_xor(a2, 16); a2 += __shfl_xor(a2, 32);
    a3 += __shfl_xor(a3, 16); a3 += __shfl_xor(a3, 32);
    den += __shfl_xor(den, 16); den += __shfl_xor(den, 32);

    if (lane < 16) {
        float inv = 1.f / (den + 1e-16f);
        float v0 = a0 * inv, v1 = a1 * inv, v2 = a2 * inv, v3 = a3 * inv;
        v0 = v0 > 0.f ? v0 : (__expf(v0) - 1.f);
        v1 = v1 > 0.f ? v1 : (__expf(v1) - 1.f);
        v2 = v2 > 0.f ? v2 : (__expf(v2) - 1.f);
        v3 = v3 > 0.f ? v3 : (__expf(v3) - 1.f);
        ushort4 r;
        r.x = f2bf(v0); r.y = f2bf(v1); r.z = f2bf(v2); r.w = f2bf(v3);
        *(ushort4*)&hb[(size_t)d * D1 + (li << 2)] = r;
    }
}

// ---------------------------------------------------------------------------
// GEMM2: xh2b[N,40] = bf16( h[N,64] @ W2[64,40] )
// ---------------------------------------------------------------------------
__global__ void gemm2(const unsigned short* __restrict__ hb,
                      const float* __restrict__ W2,
                      unsigned short* __restrict__ xh2b) {
    int gid = blockIdx.x * blockDim.x + threadIdx.x;
    if (gid >= N_NODES * NCLS) return;
    int n = gid / NCLS, c = gid % NCLS;
    const uint4* hr = (const uint4*)(hb + (size_t)n * D1);
    float s = 0.f;
    #pragma unroll
    for (int q = 0; q < 8; ++q) {
        uint4 u = hr[q];
        int k = q * 8;
        s = fmaf(bf2f((unsigned short)(u.x & 0xffff)), W2[(k + 0) * NCLS + c], s);
        s = fmaf(bf2f((unsigned short)(u.x >> 16)),    W2[(k + 1) * NCLS + c], s);
        s = fmaf(bf2f((unsigned short)(u.y & 0xffff)), W2[(k + 2) * NCLS + c], s);
        s = fmaf(bf2f((unsigned short)(u.y >> 16)),    W2[(k + 3) * NCLS + c], s);
        s = fmaf(bf2f((unsigned short)(u.z & 0xffff)), W2[(k + 4) * NCLS + c], s);
        s = fmaf(bf2f((unsigned short)(u.z >> 16)),    W2[(k + 5) * NCLS + c], s);
        s = fmaf(bf2f((unsigned short)(u.w & 0xffff)), W2[(k + 6) * NCLS + c], s);
        s = fmaf(bf2f((unsigned short)(u.w >> 16)),    W2[(k + 7) * NCLS + c], s);
    }
    xh2b[gid] = f2bf(s);
}

// ---------------------------------------------------------------------------
// A2: per-node attention coefficients for layer 2 (bf16 features)
// ---------------------------------------------------------------------------
__global__ void a2k(const unsigned short* __restrict__ xh2b,
                    const float* __restrict__ att_s2, const float* __restrict__ att_d2,
                    const int* __restrict__ idxp,
                    float* __restrict__ a_src2, float* __restrict__ a_dst2) {
    int n = blockIdx.x * blockDim.x + threadIdx.x;
    if (n >= N_NODES) return;
    float sign = (idxp[0] == 1) ? -1.f : 1.f;
    const uint4* xr = (const uint4*)(xh2b + (size_t)n * NCLS);
    float ss = 0.f, sd = 0.f;
    #pragma unroll
    for (int q = 0; q < 5; ++q) {
        uint4 u = xr[q];
        int k = q * 8;
        float v[8];
        v[0] = bf2f((unsigned short)(u.x & 0xffff)); v[1] = bf2f((unsigned short)(u.x >> 16));
        v[2] = bf2f((unsigned short)(u.y & 0xffff)); v[3] = bf2f((unsigned short)(u.y >> 16));
        v[4] = bf2f((unsigned short)(u.z & 0xffff)); v[5] = bf2f((unsigned short)(u.z >> 16));
        v[6] = bf2f((unsigned short)(u.w & 0xffff)); v[7] = bf2f((unsigned short)(u.w >> 16));
        #pragma unroll
        for (int j = 0; j < 8; ++j) {
            ss += v[j] * att_s2[k + j];
            sd += v[j] * att_d2[k + j];
        }
    }
    a_src2[n] = sign * ss;
    a_dst2[n] = sign * sd;
}

// ---------------------------------------------------------------------------
// AGG2: one wave per destination; 4 edges in flight; fused bias -> out.
// ---------------------------------------------------------------------------
__global__ __launch_bounds__(256) void agg2(const int* __restrict__ rowptr,
                                            const int* __restrict__ ssrc,
                                            const unsigned short* __restrict__ xh2b,
                                            const float* __restrict__ a_src2,
                                            const float* __restrict__ a_dst2,
                                            const float* __restrict__ bias2,
                                            float* __restrict__ out) {
    int wid  = (blockIdx.x * 256 + threadIdx.x) >> 6;
    int lane = threadIdx.x & 63;
    if (wid >= N_NODES) return;
    const int d  = wid;
    const int li = lane & 15;
    const int q  = lane >> 4;
    const bool act = li < (NCLS / 4);

    const float adh = a_dst2[d];
    float a0 = 0.f, a1 = 0.f, a2 = 0.f, a3 = 0.f, den = 0.f;
    if (q == 0) {
        float e0 = __expf(lrelu(a_src2[d] + adh));
        if (act) {
            ushort4 v = *(const ushort4*)&xh2b[(size_t)d * NCLS + (li << 2)];
            a0 = e0 * bf2f(v.x); a1 = e0 * bf2f(v.y);
            a2 = e0 * bf2f(v.z); a3 = e0 * bf2f(v.w);
        }
        den = e0;
    }

    const int beg = rowptr[d], end = rowptr[d + 1];
    for (int p = beg + q; p < end; p += 4) {
        int s = ssrc[p];
        float e = __expf(lrelu(a_src2[s] + adh));
        if (act) {
            ushort4 v = *(const ushort4*)&xh2b[(size_t)s * NCLS + (li << 2)];
            a0 = fmaf(e, bf2f(v.x), a0);
            a1 = fmaf(e, bf2f(v.y), a1);
            a2 = fmaf(e, bf2f(v.z), a2);
            a3 = fmaf(e, bf2f(v.w), a3);
        }
        den += e;
    }

    a0 += __shfl_xor(a0, 16); a0 += __shfl_xor(a0, 32);
    a1 += __shfl_xor(a1, 16); a1 += __shfl_xor(a1, 32);
    a2 += __shfl_xor(a2, 16); a2 += __shfl_xor(a2, 32);
    a3 += __shfl_xor(a3, 16); a3 += __shfl_xor(a3, 32);
    den += __shfl_xor(den, 16); den += __shfl_xor(den, 32);

    if (lane < 16 && act) {
        float inv = 1.f / (den + 1e-16f);
        float4 bv = *(const float4*)&bias2[li << 2];
        float4 r;
        r.x = a0 * inv + bv.x;
        r.y = a1 * inv + bv.y;
        r.z = a2 * inv + bv.z;
        r.w = a3 * inv + bv.w;
        *(float4*)&out[(size_t)d * NCLS + (li << 2)] = r;
    }
}

// ---------------------------------------------------------------------------
extern "C" void kernel_launch(void* const* d_in, const int* in_sizes, int n_in,
                              void* d_out, int out_size, void* d_ws, size_t ws_size,
                              hipStream_t stream) {
    const float* x    = (const float*)d_in[0];
    const float* W1   = (const float*)d_in[1];
    const float* as1w = (const float*)d_in[2];
    const float* ad1w = (const float*)d_in[3];
    const float* W2   = (const float*)d_in[4];
    const float* as2w = (const float*)d_in[5];
    const float* ad2w = (const float*)d_in[6];
    const float* b2   = (const float*)d_in[7];
    const int*   ei   = (const int*)d_in[8];
    const int*   idxp = (const int*)d_in[9];
    float* out = (float*)d_out;

    // workspace layout
    unsigned short* xh1b = (unsigned short*)d_ws;        // [N*64] bf16
    unsigned short* hb   = xh1b + (size_t)N_NODES * D1;  // [N*64] bf16
    unsigned short* xh2b = hb + (size_t)N_NODES * D1;    // [N*40] bf16
    float* as1 = (float*)(xh2b + (size_t)N_NODES * NCLS);
    float* ad1 = as1 + (size_t)N_NODES * H1;
    float* as2 = ad1 + (size_t)N_NODES * H1;             // [N]
    float* ad2 = as2 + N_NODES;
    int*   cnt    = (int*)(ad2 + N_NODES);               // [N]
    int*   pre    = cnt + N_NODES;                       // [N]
    int*   rowptr = pre + N_NODES;                       // [N+1]
    int*   wofs   = rowptr + (N_NODES + 1);              // [N]
    int*   bsum   = wofs + N_NODES;                      // [128]
    int*   ssrc   = bsum + 128;                          // [E]

    const int NB = (N_NODES + 1023) / 1024;

    // ---- CSR hist + scans ----
    hipMemsetAsync(cnt, 0, (size_t)N_NODES * sizeof(int), stream);
    k_hist<<<(N_EDGES + 255) / 256, 256, 0, stream>>>(ei, cnt);
    k_scan1<<<NB, 256, 0, stream>>>(cnt, pre, bsum);
    k_scan2<<<1, 128, 0, stream>>>(bsum, NB);
    k_scan3<<<(N_NODES + 256) / 256, 256, 0, stream>>>(pre, bsum, rowptr, wofs);

    // ---- fused GEMM1 || scatter ----
    gemm1_scatter<<<G_GEMM + G_SCAT, 256, 0, stream>>>(x, W1, xh1b, ei, wofs, ssrc);

    // ---- layer 1 rest ----
    a1k<<<(N_NODES * H1 + 255) / 256, 256, 0, stream>>>(xh1b, as1w, ad1w, idxp, as1, ad1);
    agg1<<<(N_NODES * 64 + 255) / 256, 256, 0, stream>>>(rowptr, ssrc, xh1b, as1, ad1, hb);

    // ---- layer 2 ----
    gemm2<<<(N_NODES * NCLS + 255) / 256, 256, 0, stream>>>(hb, W2, xh2b);
    a2k<<<(N_NODES + 255) / 256, 256, 0, stream>>>(xh2b, as2w, ad2w, idxp, as2, ad2);
    agg2<<<(N_NODES * 64 + 255) / 256, 256, 0, stream>>>(rowptr, ssrc, xh2b, as2, ad2, b2, out);
}

// Round 8
// 444.714 us; speedup vs baseline: 2.6233x; 1.0338x over previous
//
#include <hip/hip_runtime.h>

#define N_NODES 100000
#define N_EDGES 1600000
#define F_IN    501
#define H1      8
#define C1      8
#define D1      64   // H1*C1
#define NCLS    40

typedef __attribute__((ext_vector_type(8))) short bf16x8;
typedef __attribute__((ext_vector_type(4))) float f32x4;

__device__ __forceinline__ float lrelu(float x) { return x > 0.f ? x : 0.2f * x; }

__device__ __forceinline__ unsigned short f2bf(float f) {
    unsigned u = __float_as_uint(f);
    u += 0x7FFFu + ((u >> 16) & 1u);
    return (unsigned short)(u >> 16);
}
__device__ __forceinline__ float bf2f(unsigned short u) {
    return __uint_as_float(((unsigned)u) << 16);
}

// ---------------------------------------------------------------------------
// GEMM1 (MFMA bf16, barrier-free K-loop):
//   xh1b[N,64] = bf16( x[N,501] @ W1[501,64] )
// W1 staged ONCE into LDS as bf16 [64 cols][512 k] with XOR swizzle (64 KB).
// 8 waves/block, each wave owns 16 rows; A streams per-lane from global with
// depth-4 register prefetch. No __syncthreads in the K-loop.
// ---------------------------------------------------------------------------
__global__ __launch_bounds__(512) void gemm1(const float* __restrict__ x,
                                             const float* __restrict__ W1,
                                             unsigned short* __restrict__ xh1b) {
    __shared__ unsigned short Bs[64 * 512];   // 64 KB, [col][k], swizzled

    const int tid = threadIdx.x;

    // ---- one-time B staging: W1[k][n] -> Bs[n][k] (bf16, swizzled) ----
    for (int i = tid; i < F_IN * 64; i += 512) {
        int k = i >> 6, n = i & 63;           // coalesced read of W1
        int byte = (n << 10) + (k << 1);
        byte ^= (n & 7) << 4;
        Bs[byte >> 1] = f2bf(W1[i]);
    }
    if (tid < 64) {                            // zero tail k = 501..511
        #pragma unroll
        for (int k = F_IN; k < 512; ++k) {
            int byte = (tid << 10) + (k << 1);
            byte ^= (tid & 7) << 4;
            Bs[byte >> 1] = 0;
        }
    }
    __syncthreads();                           // the only barrier

    const int lane = tid & 63;
    const int wave = tid >> 6;
    const int lr   = lane & 15;                // A row / B col within frag
    const int hi   = lane >> 4;                // 0..3
    const int lk   = hi * 8;                   // k offset within 32-step

    const int row  = blockIdx.x * 128 + wave * 16 + lr;
    const int rowc = row < N_NODES ? row : N_NODES - 1;   // clamp (stores guarded)
    const float* aptr = x + (size_t)rowc * F_IN + lk;

    f32x4 acc[4] = {};
    float av[4][8];

    // prefetch K-steps 0..3
    #pragma unroll
    for (int pf = 0; pf < 4; ++pf)
        #pragma unroll
        for (int j = 0; j < 8; ++j)
            av[pf][j] = aptr[pf * 32 + j];

    #pragma unroll
    for (int s = 0; s < 16; ++s) {
        // convert this step's A fragment to bf16
        bf16x8 a;
        #pragma unroll
        for (int j = 0; j < 8; ++j) a[j] = (short)f2bf(av[s & 3][j]);

        // prefetch step s+4 (loads stay in flight under the MFMAs)
        if (s + 4 < 15) {
            #pragma unroll
            for (int j = 0; j < 8; ++j)
                av[s & 3][j] = aptr[(s + 4) * 32 + j];
        } else if (s + 4 == 15) {              // tail step: guard k < 501
            #pragma unroll
            for (int j = 0; j < 8; ++j) {
                int k = 15 * 32 + lk + j;
                av[s & 3][j] = (k < F_IN) ? aptr[15 * 32 + j] : 0.f;
            }
        }

        // B fragments from LDS (swizzled, conflict-free) + MFMA
        #pragma unroll
        for (int n = 0; n < 4; ++n) {
            int c = n * 16 + lr;
            int byte = (c << 10) + ((s * 32 + lk) << 1);
            byte ^= (c & 7) << 4;
            bf16x8 b = *(const bf16x8*)((const char*)Bs + byte);
            acc[n] = __builtin_amdgcn_mfma_f32_16x16x32_bf16(a, b, acc[n], 0, 0, 0);
        }
    }

    // epilogue: row = base + hi*4 + r, col = n*16 + lr
    int rbase = blockIdx.x * 128 + wave * 16 + hi * 4;
    #pragma unroll
    for (int n = 0; n < 4; ++n) {
        int col = n * 16 + lr;
        #pragma unroll
        for (int r = 0; r < 4; ++r) {
            int grow = rbase + r;
            if (grow < N_NODES) xh1b[(size_t)grow * D1 + col] = f2bf(acc[n][r]);
        }
    }
}

// ---------------------------------------------------------------------------
// A1: per-(node,head) attention coefficients for layer 1 (bf16 features)
// ---------------------------------------------------------------------------
__global__ void a1k(const unsigned short* __restrict__ xh1b,
                    const float* __restrict__ att_s, const float* __restrict__ att_d,
                    const int* __restrict__ idxp,
                    float* __restrict__ a_src, float* __restrict__ a_dst) {
    int gid = blockIdx.x * blockDim.x + threadIdx.x;
    if (gid >= N_NODES * H1) return;
    int n = gid >> 3, h = gid & 7;
    float sign = (idxp[0] == 1) ? -1.f : 1.f;
    uint4 u = *(const uint4*)(xh1b + (size_t)n * D1 + h * C1);
    float v[8];
    v[0] = bf2f((unsigned short)(u.x & 0xffff)); v[1] = bf2f((unsigned short)(u.x >> 16));
    v[2] = bf2f((unsigned short)(u.y & 0xffff)); v[3] = bf2f((unsigned short)(u.y >> 16));
    v[4] = bf2f((unsigned short)(u.z & 0xffff)); v[5] = bf2f((unsigned short)(u.z >> 16));
    v[6] = bf2f((unsigned short)(u.w & 0xffff)); v[7] = bf2f((unsigned short)(u.w >> 16));
    float ss = 0.f, sd = 0.f;
    #pragma unroll
    for (int c = 0; c < C1; ++c) {
        ss += v[c] * att_s[h * C1 + c];
        sd += v[c] * att_d[h * C1 + c];
    }
    a_src[gid] = sign * ss;
    a_dst[gid] = sign * sd;
}

// ---------------------------------------------------------------------------
// CSR build: histogram -> scan -> scatter (nontemporal ei reads keep the
// streaming edge list from evicting ssrc/cnt lines out of L2)
// ---------------------------------------------------------------------------
__global__ void k_hist(const int* __restrict__ ei, int* __restrict__ cnt) {
    int e = blockIdx.x * blockDim.x + threadIdx.x;
    if (e >= N_EDGES) return;
    int d = __builtin_nontemporal_load(ei + N_EDGES + e);
    atomicAdd(&cnt[d], 1);
}

__global__ __launch_bounds__(256) void k_scan1(const int* __restrict__ cnt,
                                               int* __restrict__ pre,
                                               int* __restrict__ bsum) {
    __shared__ int s[256];
    int t = threadIdx.x;
    int base = blockIdx.x * 1024 + t * 4;
    int v[4], sum = 0;
    #pragma unroll
    for (int i = 0; i < 4; ++i) {
        v[i] = (base + i < N_NODES) ? cnt[base + i] : 0;
        sum += v[i];
    }
    s[t] = sum;
    __syncthreads();
    for (int off = 1; off < 256; off <<= 1) {
        int x = 0;
        if (t >= off) x = s[t - off];
        __syncthreads();
        if (t >= off) s[t] += x;
        __syncthreads();
    }
    int run = s[t] - sum;
    if (t == 255) bsum[blockIdx.x] = s[255];
    #pragma unroll
    for (int i = 0; i < 4; ++i) {
        if (base + i < N_NODES) pre[base + i] = run;
        run += v[i];
    }
}

__global__ void k_scan2(int* __restrict__ bsum, int nb) {
    __shared__ int s[128];
    int t = threadIdx.x;
    int v = (t < nb) ? bsum[t] : 0;
    s[t] = v;
    __syncthreads();
    for (int off = 1; off < 128; off <<= 1) {
        int x = 0;
        if (t >= off) x = s[t - off];
        __syncthreads();
        if (t >= off) s[t] += x;
        __syncthreads();
    }
    if (t < nb) bsum[t] = s[t] - v;
}

__global__ void k_scan3(const int* __restrict__ pre, const int* __restrict__ bsum,
                        int* __restrict__ rowptr, int* __restrict__ wofs) {
    int i = blockIdx.x * blockDim.x + threadIdx.x;
    if (i < N_NODES) {
        int r = pre[i] + bsum[i >> 10];
        rowptr[i] = r;
        wofs[i]   = r;
    } else if (i == N_NODES) {
        rowptr[N_NODES] = N_EDGES;
    }
}

__global__ void k_scatter(const int* __restrict__ ei, int* __restrict__ wofs,
                          int* __restrict__ ssrc) {
    int e = blockIdx.x * blockDim.x + threadIdx.x;
    if (e >= N_EDGES) return;
    int s = __builtin_nontemporal_load(ei + e);
    int d = __builtin_nontemporal_load(ei + N_EDGES + e);
    int p = atomicAdd(&wofs[d], 1);
    ssrc[p] = s;
}

// ---------------------------------------------------------------------------
// AGG1: one wave per destination; 4 edges in flight (quarter-waves).
// ---------------------------------------------------------------------------
__global__ __launch_bounds__(256) void agg1(const int* __restrict__ rowptr,
                                            const int* __restrict__ ssrc,
                                            const unsigned short* __restrict__ xh1b,
                                            const float* __restrict__ a_src,
                                            const float* __restrict__ a_dst,
                                            unsigned short* __restrict__ hb) {
    int wid  = (blockIdx.x * 256 + threadIdx.x) >> 6;
    int lane = threadIdx.x & 63;
    if (wid >= N_NODES) return;
    const int d  = wid;
    const int li = lane & 15;
    const int q  = lane >> 4;
    const int hh = li >> 1;

    const float adh = a_dst[d * H1 + hh];
    float a0 = 0.f, a1 = 0.f, a2 = 0.f, a3 = 0.f, den = 0.f;
    if (q == 0) {
        float e0 = __expf(lrelu(a_src[d * H1 + hh] + adh));
        ushort4 v = *(const ushort4*)&xh1b[(size_t)d * D1 + (li << 2)];
        a0 = e0 * bf2f(v.x); a1 = e0 * bf2f(v.y);
        a2 = e0 * bf2f(v.z); a3 = e0 * bf2f(v.w);
        den = e0;
    }

    const int beg = rowptr[d], end = rowptr[d + 1];
    for (int p = beg + q; p < end; p += 4) {
        int s = ssrc[p];
        float e = __expf(lrelu(a_src[s * H1 + hh] + adh));
        ushort4 v = *(const ushort4*)&xh1b[(size_t)s * D1 + (li << 2)];
        a0 = fmaf(e, bf2f(v.x), a0);
        a1 = fmaf(e, bf2f(v.y), a1);
        a2 = fmaf(e, bf2f(v.z), a2);
        a3 = fmaf(e, bf2f(v.w), a3);
        den += e;
    }

    a0 += __shfl_xor(a0, 16); a0 += __shfl_xor(a0, 32);
    a1 += __shfl_xor(a1, 16); a1 += __shfl_xor(a1, 32);
    a2 += __shfl_xor(a2, 16); a2 += __shfl_xor(a2, 32);
    a3 += __shfl_xor(a3, 16); a3 += __shfl_xor(a3, 32);
    den += __shfl_xor(den, 16); den += __shfl_xor(den, 32);

    if (lane < 16) {
        float inv = 1.f / (den + 1e-16f);
        float v0 = a0 * inv, v1 = a1 * inv, v2 = a2 * inv, v3 = a3 * inv;
        v0 = v0 > 0.f ? v0 : (__expf(v0) - 1.f);
        v1 = v1 > 0.f ? v1 : (__expf(v1) - 1.f);
        v2 = v2 > 0.f ? v2 : (__expf(v2) - 1.f);
        v3 = v3 > 0.f ? v3 : (__expf(v3) - 1.f);
        ushort4 r;
        r.x = f2bf(v0); r.y = f2bf(v1); r.z = f2bf(v2); r.w = f2bf(v3);
        *(ushort4*)&hb[(size_t)d * D1 + (li << 2)] = r;
    }
}

// ---------------------------------------------------------------------------
// GEMM2: xh2b[N,40] = bf16( h[N,64] @ W2[64,40] )
// ---------------------------------------------------------------------------
__global__ void gemm2(const unsigned short* __restrict__ hb,
                      const float* __restrict__ W2,
                      unsigned short* __restrict__ xh2b) {
    int gid = blockIdx.x * blockDim.x + threadIdx.x;
    if (gid >= N_NODES * NCLS) return;
    int n = gid / NCLS, c = gid % NCLS;
    const uint4* hr = (const uint4*)(hb + (size_t)n * D1);
    float s = 0.f;
    #pragma unroll
    for (int q = 0; q < 8; ++q) {
        uint4 u = hr[q];
        int k = q * 8;
        s = fmaf(bf2f((unsigned short)(u.x & 0xffff)), W2[(k + 0) * NCLS + c], s);
        s = fmaf(bf2f((unsigned short)(u.x >> 16)),    W2[(k + 1) * NCLS + c], s);
        s = fmaf(bf2f((unsigned short)(u.y & 0xffff)), W2[(k + 2) * NCLS + c], s);
        s = fmaf(bf2f((unsigned short)(u.y >> 16)),    W2[(k + 3) * NCLS + c], s);
        s = fmaf(bf2f((unsigned short)(u.z & 0xffff)), W2[(k + 4) * NCLS + c], s);
        s = fmaf(bf2f((unsigned short)(u.z >> 16)),    W2[(k + 5) * NCLS + c], s);
        s = fmaf(bf2f((unsigned short)(u.w & 0xffff)), W2[(k + 6) * NCLS + c], s);
        s = fmaf(bf2f((unsigned short)(u.w >> 16)),    W2[(k + 7) * NCLS + c], s);
    }
    xh2b[gid] = f2bf(s);
}

// ---------------------------------------------------------------------------
// A2: per-node attention coefficients for layer 2 (bf16 features)
// ---------------------------------------------------------------------------
__global__ void a2k(const unsigned short* __restrict__ xh2b,
                    const float* __restrict__ att_s2, const float* __restrict__ att_d2,
                    const int* __restrict__ idxp,
                    float* __restrict__ a_src2, float* __restrict__ a_dst2) {
    int n = blockIdx.x * blockDim.x + threadIdx.x;
    if (n >= N_NODES) return;
    float sign = (idxp[0] == 1) ? -1.f : 1.f;
    const uint4* xr = (const uint4*)(xh2b + (size_t)n * NCLS);
    float ss = 0.f, sd = 0.f;
    #pragma unroll
    for (int q = 0; q < 5; ++q) {
        uint4 u = xr[q];
        int k = q * 8;
        float v[8];
        v[0] = bf2f((unsigned short)(u.x & 0xffff)); v[1] = bf2f((unsigned short)(u.x >> 16));
        v[2] = bf2f((unsigned short)(u.y & 0xffff)); v[3] = bf2f((unsigned short)(u.y >> 16));
        v[4] = bf2f((unsigned short)(u.z & 0xffff)); v[5] = bf2f((unsigned short)(u.z >> 16));
        v[6] = bf2f((unsigned short)(u.w & 0xffff)); v[7] = bf2f((unsigned short)(u.w >> 16));
        #pragma unroll
        for (int j = 0; j < 8; ++j) {
            ss += v[j] * att_s2[k + j];
            sd += v[j] * att_d2[k + j];
        }
    }
    a_src2[n] = sign * ss;
    a_dst2[n] = sign * sd;
}

// ---------------------------------------------------------------------------
// AGG2: one wave per destination; 4 edges in flight; fused bias -> out.
// ---------------------------------------------------------------------------
__global__ __launch_bounds__(256) void agg2(const int* __restrict__ rowptr,
                                            const int* __restrict__ ssrc,
                                            const unsigned short* __restrict__ xh2b,
                                            const float* __restrict__ a_src2,
                                            const float* __restrict__ a_dst2,
                                            const float* __restrict__ bias2,
                                            float* __restrict__ out) {
    int wid  = (blockIdx.x * 256 + threadIdx.x) >> 6;
    int lane = threadIdx.x & 63;
    if (wid >= N_NODES) return;
    const int d  = wid;
    const int li = lane & 15;
    const int q  = lane >> 4;
    const bool act = li < (NCLS / 4);

    const float adh = a_dst2[d];
    float a0 = 0.f, a1 = 0.f, a2 = 0.f, a3 = 0.f, den = 0.f;
    if (q == 0) {
        float e0 = __expf(lrelu(a_src2[d] + adh));
        if (act) {
            ushort4 v = *(const ushort4*)&xh2b[(size_t)d * NCLS + (li << 2)];
            a0 = e0 * bf2f(v.x); a1 = e0 * bf2f(v.y);
            a2 = e0 * bf2f(v.z); a3 = e0 * bf2f(v.w);
        }
        den = e0;
    }

    const int beg = rowptr[d], end = rowptr[d + 1];
    for (int p = beg + q; p < end; p += 4) {
        int s = ssrc[p];
        float e = __expf(lrelu(a_src2[s] + adh));
        if (act) {
            ushort4 v = *(const ushort4*)&xh2b[(size_t)s * NCLS + (li << 2)];
            a0 = fmaf(e, bf2f(v.x), a0);
            a1 = fmaf(e, bf2f(v.y), a1);
            a2 = fmaf(e, bf2f(v.z), a2);
            a3 = fmaf(e, bf2f(v.w), a3);
        }
        den += e;
    }

    a0 += __shfl_xor(a0, 16); a0 += __shfl_xor(a0, 32);
    a1 += __shfl_xor(a1, 16); a1 += __shfl_xor(a1, 32);
    a2 += __shfl_xor(a2, 16); a2 += __shfl_xor(a2, 32);
    a3 += __shfl_xor(a3, 16); a3 += __shfl_xor(a3, 32);
    den += __shfl_xor(den, 16); den += __shfl_xor(den, 32);

    if (lane < 16 && act) {
        float inv = 1.f / (den + 1e-16f);
        float4 bv = *(const float4*)&bias2[li << 2];
        float4 r;
        r.x = a0 * inv + bv.x;
        r.y = a1 * inv + bv.y;
        r.z = a2 * inv + bv.z;
        r.w = a3 * inv + bv.w;
        *(float4*)&out[(size_t)d * NCLS + (li << 2)] = r;
    }
}

// ---------------------------------------------------------------------------
extern "C" void kernel_launch(void* const* d_in, const int* in_sizes, int n_in,
                              void* d_out, int out_size, void* d_ws, size_t ws_size,
                              hipStream_t stream) {
    const float* x    = (const float*)d_in[0];
    const float* W1   = (const float*)d_in[1];
    const float* as1w = (const float*)d_in[2];
    const float* ad1w = (const float*)d_in[3];
    const float* W2   = (const float*)d_in[4];
    const float* as2w = (const float*)d_in[5];
    const float* ad2w = (const float*)d_in[6];
    const float* b2   = (const float*)d_in[7];
    const int*   ei   = (const int*)d_in[8];
    const int*   idxp = (const int*)d_in[9];
    float* out = (float*)d_out;

    // workspace layout
    unsigned short* xh1b = (unsigned short*)d_ws;        // [N*64] bf16
    unsigned short* hb   = xh1b + (size_t)N_NODES * D1;  // [N*64] bf16
    unsigned short* xh2b = hb + (size_t)N_NODES * D1;    // [N*40] bf16
    float* as1 = (float*)(xh2b + (size_t)N_NODES * NCLS);
    float* ad1 = as1 + (size_t)N_NODES * H1;
    float* as2 = ad1 + (size_t)N_NODES * H1;             // [N]
    float* ad2 = as2 + N_NODES;
    int*   cnt    = (int*)(ad2 + N_NODES);               // [N]
    int*   pre    = cnt + N_NODES;                       // [N]
    int*   rowptr = pre + N_NODES;                       // [N+1]
    int*   wofs   = rowptr + (N_NODES + 1);              // [N]
    int*   bsum   = wofs + N_NODES;                      // [128]
    int*   ssrc   = bsum + 128;                          // [E]

    const int NB = (N_NODES + 1023) / 1024;

    // ---- CSR build ----
    hipMemsetAsync(cnt, 0, (size_t)N_NODES * sizeof(int), stream);
    k_hist<<<(N_EDGES + 255) / 256, 256, 0, stream>>>(ei, cnt);
    k_scan1<<<NB, 256, 0, stream>>>(cnt, pre, bsum);
    k_scan2<<<1, 128, 0, stream>>>(bsum, NB);
    k_scan3<<<(N_NODES + 256) / 256, 256, 0, stream>>>(pre, bsum, rowptr, wofs);
    k_scatter<<<(N_EDGES + 255) / 256, 256, 0, stream>>>(ei, wofs, ssrc);

    // ---- layer 1 ----
    gemm1<<<(N_NODES + 127) / 128, 512, 0, stream>>>(x, W1, xh1b);
    a1k<<<(N_NODES * H1 + 255) / 256, 256, 0, stream>>>(xh1b, as1w, ad1w, idxp, as1, ad1);
    agg1<<<(N_NODES * 64 + 255) / 256, 256, 0, stream>>>(rowptr, ssrc, xh1b, as1, ad1, hb);

    // ---- layer 2 ----
    gemm2<<<(N_NODES * NCLS + 255) / 256, 256, 0, stream>>>(hb, W2, xh2b);
    a2k<<<(N_NODES + 255) / 256, 256, 0, stream>>>(xh2b, as2w, ad2w, idxp, as2, ad2);
    agg2<<<(N_NODES * 64 + 255) / 256, 256, 0, stream>>>(rowptr, ssrc, xh2b, as2, ad2, b2, out);
}